// Round 6
// baseline (446.611 us; speedup 1.0000x reference)
//
#include <hip/hip_runtime.h>
#include <float.h>

#define N_PTS 262144
#define K_CL  1024
#define D     64
#define PTS_PER_WAVE   32
#define WAVES_PER_BLK  4
#define PTS_PER_BLK    (PTS_PER_WAVE * WAVES_PER_BLK)   // 128
#define NTILE 8              // 8 tiles of 128 centroids
#define MARGIN_S 0.5f        // score margin (distance margin 1.0; fp16 err bound ~0.07)
#define CAND_CAP 6

typedef _Float16 f16;
typedef _Float16 half8 __attribute__((ext_vector_type(8)));
typedef float    f32x4 __attribute__((ext_vector_type(4)));

// ---- prep: csq (exact fp32), csqhn = -0.5*csq, cent16 = fp16 linear
__global__ __launch_bounds__(256) void prep_kernel(const float* __restrict__ cent,
                                                   float* __restrict__ csq,
                                                   float* __restrict__ csqhn,
                                                   f16* __restrict__ cent16) {
    int k = blockIdx.x * 256 + threadIdx.x;
    if (k >= K_CL) return;
    const float* row = &cent[(size_t)k * D];
    float s = 0.f;
    #pragma unroll
    for (int d = 0; d < D; ++d) s = fmaf(row[d], row[d], s);
    csq[k]   = s;
    csqhn[k] = -0.5f * s;
    #pragma unroll
    for (int ch = 0; ch < 8; ++ch) {
        half8 h;
        #pragma unroll
        for (int e = 0; e < 8; ++e) h[e] = (f16)row[ch * 8 + e];
        *reinterpret_cast<half8*>(&cent16[(size_t)k * D + ch * 8]) = h;
    }
}

// exact fp32 distance, identical arithmetic to the accepted round-1 kernel
__device__ __forceinline__ float exact_dist(const float* __restrict__ xr,
                                            const float* __restrict__ cr,
                                            float xsq, float cs) {
    float dot = 0.f;
    #pragma unroll
    for (int d = 0; d < D; ++d) dot = fmaf(xr[d], cr[d], dot);
    return (xsq - 2.0f * dot) + cs;
}

__device__ __forceinline__ half8 ld_half8(const f16* p) {
    return *reinterpret_cast<const half8*>(p);
}

__device__ __forceinline__ half8 point_frag(const float* __restrict__ batch,
                                            int prow, int chunk) {
    const float* src = &batch[(size_t)prow * D + chunk * 8];
    float4 u0 = *reinterpret_cast<const float4*>(src);
    float4 u1 = *reinterpret_cast<const float4*>(src + 4);
    half8 h;
    h[0] = (f16)u0.x; h[1] = (f16)u0.y; h[2] = (f16)u0.z; h[3] = (f16)u0.w;
    h[4] = (f16)u1.x; h[5] = (f16)u1.y; h[6] = (f16)u1.z; h[7] = (f16)u1.w;
    return h;
}

__device__ __forceinline__ float vmax4(const f32x4& a) {
    return fmaxf(fmaxf(a.x, a.y), fmaxf(a.z, a.w));
}

__device__ __forceinline__ void collect(const f32x4& a, float thr, int cbase, int& cnt,
                                        int& s0, int& s1, int& s2, int& s3, int& s4, int& s5) {
    if (vmax4(a) >= thr) {
        #pragma unroll
        for (int r = 0; r < 4; ++r) {
            if (a[r] >= thr) {
                int c = cbase + r;
                if      (cnt == 0) s0 = c;
                else if (cnt == 1) s1 = c;
                else if (cnt == 2) s2 = c;
                else if (cnt == 3) s3 = c;
                else if (cnt == 4) s4 = c;
                else if (cnt == 5) s5 = c;
                cnt++;
            }
        }
    }
}

__device__ __forceinline__ void resolve(const float* __restrict__ batch,
                                        const float* __restrict__ cent,
                                        const float* __restrict__ csq,
                                        int prow, int hi, int cnt,
                                        int s0, int s1, int s2, int s3, int s4, int s5,
                                        float& bd, int& bi) {
    bd = FLT_MAX; bi = 0x7fffffff;
    if (cnt == 0) return;
    const float* xr = &batch[(size_t)prow * D];
    float xsq = 0.f;
    #pragma unroll
    for (int d = 0; d < D; ++d) xsq = fmaf(xr[d], xr[d], xsq);
    if (cnt <= CAND_CAP) {
        #pragma unroll
        for (int r = 0; r < CAND_CAP; ++r) {
            int c = (r == 0) ? s0 : (r == 1) ? s1 : (r == 2) ? s2
                  : (r == 3) ? s3 : (r == 4) ? s4 : s5;
            if (r < cnt) {
                float dd = exact_dist(xr, &cent[(size_t)c * D], xsq, csq[c]);
                if (dd < bd || (dd == bd && c < bi)) { bd = dd; bi = c; }
            }
        }
    } else {  // overflow (P ~ 0 with final-max threshold): exact scan of lane's slice
        for (int t16 = 0; t16 < 64; ++t16) {
            #pragma unroll
            for (int r = 0; r < 4; ++r) {
                int c = t16 * 16 + hi * 4 + r;
                float dd = exact_dist(xr, &cent[(size_t)c * D], xsq, csq[c]);
                if (dd < bd || (dd == bd && c < bi)) { bd = dd; bi = c; }
            }
        }
    }
}

__global__ __launch_bounds__(256, 8) void assign_kernel(
    const float* __restrict__ batch,
    const f16*   __restrict__ cent16,
    const float* __restrict__ csq,
    const float* __restrict__ csqhn,
    const float* __restrict__ cent,
    float* __restrict__ out_assign)
{
    const int tid   = threadIdx.x;
    const int wave  = tid >> 6;
    const int lane  = tid & 63;
    const int lo    = lane & 15;
    const int hi    = lane >> 4;
    const int wbase = (blockIdx.x * WAVES_PER_BLK + wave) * PTS_PER_WAVE;

    const int pr0 = wbase + lo;
    const int pr1 = wbase + 16 + lo;

    // loop-invariant point fragments in registers
    const half8 p0a = point_frag(batch, pr0, hi), p0b = point_frag(batch, pr0, 4 + hi);
    const half8 p1a = point_frag(batch, pr1, hi), p1b = point_frag(batch, pr1, 4 + hi);

    // =================== PASS 1: branch-free final max ===================
    float m0 = -FLT_MAX, m1 = -FLT_MAX;
    for (int t = 0; t < NTILE; ++t) {
        const int base = t * 128;
        #pragma unroll
        for (int m = 0; m < 8; ++m) {
            const int row = base + m * 16 + lo;
            const half8 cf0 = ld_half8(&cent16[(size_t)row * D + hi * 8]);
            const half8 cf1 = ld_half8(&cent16[(size_t)row * D + (4 + hi) * 8]);
            const f32x4 ch  = *reinterpret_cast<const f32x4*>(&csqhn[base + m * 16 + hi * 4]);
            f32x4 a0 = ch, a1 = ch;
            a0 = __builtin_amdgcn_mfma_f32_16x16x32_f16(cf0, p0a, a0, 0, 0, 0);
            a0 = __builtin_amdgcn_mfma_f32_16x16x32_f16(cf1, p0b, a0, 0, 0, 0);
            a1 = __builtin_amdgcn_mfma_f32_16x16x32_f16(cf0, p1a, a1, 0, 0, 0);
            a1 = __builtin_amdgcn_mfma_f32_16x16x32_f16(cf1, p1b, a1, 0, 0, 0);
            m0 = fmaxf(m0, vmax4(a0));
            m1 = fmaxf(m1, vmax4(a1));
        }
    }
    m0 = fmaxf(m0, __shfl_xor(m0, 16)); m0 = fmaxf(m0, __shfl_xor(m0, 32));
    m1 = fmaxf(m1, __shfl_xor(m1, 16)); m1 = fmaxf(m1, __shfl_xor(m1, 32));
    const float t0 = m0 - MARGIN_S, t1 = m1 - MARGIN_S;

    // =================== PASS 2: collect candidates vs final threshold ===================
    int n0 = 0, n1 = 0;
    int a0c0=0,a0c1=0,a0c2=0,a0c3=0,a0c4=0,a0c5=0;
    int a1c0=0,a1c1=0,a1c2=0,a1c3=0,a1c4=0,a1c5=0;

    for (int t = 0; t < NTILE; ++t) {
        const int base = t * 128;
        #pragma unroll
        for (int m = 0; m < 8; ++m) {
            const int row = base + m * 16 + lo;
            const half8 cf0 = ld_half8(&cent16[(size_t)row * D + hi * 8]);
            const half8 cf1 = ld_half8(&cent16[(size_t)row * D + (4 + hi) * 8]);
            const f32x4 ch  = *reinterpret_cast<const f32x4*>(&csqhn[base + m * 16 + hi * 4]);
            f32x4 a0 = ch, a1 = ch;
            a0 = __builtin_amdgcn_mfma_f32_16x16x32_f16(cf0, p0a, a0, 0, 0, 0);
            a0 = __builtin_amdgcn_mfma_f32_16x16x32_f16(cf1, p0b, a0, 0, 0, 0);
            a1 = __builtin_amdgcn_mfma_f32_16x16x32_f16(cf0, p1a, a1, 0, 0, 0);
            a1 = __builtin_amdgcn_mfma_f32_16x16x32_f16(cf1, p1b, a1, 0, 0, 0);
            const int cbase = base + m * 16 + hi * 4;
            collect(a0, t0, cbase, n0, a0c0, a0c1, a0c2, a0c3, a0c4, a0c5);
            collect(a1, t1, cbase, n1, a1c0, a1c1, a1c2, a1c3, a1c4, a1c5);
        }
    }

    // =================== exact fp32 resolve (round-1 arithmetic) ===================
    float bd0, bd1;
    int   bi0, bi1;
    resolve(batch, cent, csq, pr0, hi, n0, a0c0, a0c1, a0c2, a0c3, a0c4, a0c5, bd0, bi0);
    resolve(batch, cent, csq, pr1, hi, n1, a1c0, a1c1, a1c2, a1c3, a1c4, a1c5, bd1, bi1);

    #pragma unroll
    for (int off = 16; off <= 32; off <<= 1) {
        float od; int oi;
        od = __shfl_xor(bd0, off); oi = __shfl_xor(bi0, off);
        if (od < bd0 || (od == bd0 && oi < bi0)) { bd0 = od; bi0 = oi; }
        od = __shfl_xor(bd1, off); oi = __shfl_xor(bi1, off);
        if (od < bd1 || (od == bd1 && oi < bi1)) { bd1 = od; bi1 = oi; }
    }

    if (hi == 0) {
        out_assign[pr0] = (float)bi0;
        out_assign[pr1] = (float)bi1;
    }
}

// ---- scatter with runtime nsplit-way split copies
__global__ __launch_bounds__(256) void scatter_split_kernel(
    const float* __restrict__ batch,
    const float* __restrict__ assignF,
    float* __restrict__ partial,        // [nsplit][K_CL][D]
    float* __restrict__ cnt_partial,    // [nsplit][K_CL]
    int split_mask)
{
    const int gwave = (blockIdx.x * 256 + threadIdx.x) >> 6;   // 16384 waves
    const int lane  = threadIdx.x & 63;
    const int split = blockIdx.x & split_mask;
    float* ps = &partial[(size_t)split * K_CL * D];
    float* cs = &cnt_partial[(size_t)split * K_CL];
    #pragma unroll 4
    for (int it = 0; it < 16; ++it) {
        int p = gwave * 16 + it;
        int a = (int)assignF[p];
        atomicAdd(&ps[(size_t)a * D + lane], batch[(size_t)p * D + lane]);
        if (lane == 0) atomicAdd(&cs[a], 1.0f);
    }
}

__global__ __launch_bounds__(256) void reduce_kernel(
    const float* __restrict__ partial,
    const float* __restrict__ cnt_partial,
    float* __restrict__ out_counts,
    float* __restrict__ out_sums,
    int nsplit)
{
    int idx = blockIdx.x * 256 + threadIdx.x;
    if (idx < K_CL * D) {
        float s = 0.f;
        for (int e = 0; e < nsplit; ++e) s += partial[(size_t)e * K_CL * D + idx];
        out_sums[idx] = s;
    } else if (idx < K_CL * D + K_CL) {
        int c = idx - K_CL * D;
        float s = 0.f;
        for (int e = 0; e < nsplit; ++e) s += cnt_partial[e * K_CL + c];
        out_counts[c] = s;
    }
}

// ---- fallback scatter (single-copy atomics into d_out) if ws is too small
__global__ __launch_bounds__(256) void scatter_atomic_kernel(
    const float* __restrict__ batch,
    const float* __restrict__ assignF,
    float* __restrict__ out_counts,
    float* __restrict__ out_sums)
{
    const int gwave = (blockIdx.x * 256 + threadIdx.x) >> 6;
    const int lane  = threadIdx.x & 63;
    #pragma unroll 4
    for (int it = 0; it < 16; ++it) {
        int p = gwave * 16 + it;
        int a = (int)assignF[p];
        if (lane == 0) atomicAdd(&out_counts[a], 1.0f);
        atomicAdd(&out_sums[(size_t)a * D + lane], batch[(size_t)p * D + lane]);
    }
}

extern "C" void kernel_launch(void* const* d_in, const int* in_sizes, int n_in,
                              void* d_out, int out_size, void* d_ws, size_t ws_size,
                              hipStream_t stream) {
    const float* batch = (const float*)d_in[0];
    const float* cent  = (const float*)d_in[1];
    float* out        = (float*)d_out;
    float* out_assign = out;
    float* out_counts = out + N_PTS;
    float* out_sums   = out + N_PTS + K_CL;

    float* csq    = (float*)d_ws;                                  // 4 KB
    float* csqhn  = csq + K_CL;                                    // 4 KB
    f16*   cent16 = (f16*)((char*)d_ws + 8192);                    // 128 KB
    float* partial = (float*)((char*)d_ws + 8192 + 131072);

    // pick largest nsplit that fits ws (32 -> 16 -> 8 -> fallback)
    int nsplit = 0;
    for (int ns = 32; ns >= 8; ns >>= 1) {
        size_t need = 8192 + 131072 +
                      (size_t)ns * K_CL * D * 4 + (size_t)ns * K_CL * 4;
        if (ws_size >= need) { nsplit = ns; break; }
    }

    prep_kernel<<<K_CL / 256, 256, 0, stream>>>(cent, csq, csqhn, cent16);
    assign_kernel<<<N_PTS / PTS_PER_BLK, 256, 0, stream>>>(
        batch, cent16, csq, csqhn, cent, out_assign);

    if (nsplit > 0) {
        float* cnt_partial = partial + (size_t)nsplit * K_CL * D;
        hipMemsetAsync(partial, 0,
                       (size_t)(nsplit * K_CL * D + nsplit * K_CL) * sizeof(float), stream);
        scatter_split_kernel<<<N_PTS / (16 * 4), 256, 0, stream>>>(
            batch, out_assign, partial, cnt_partial, nsplit - 1);
        reduce_kernel<<<(K_CL * D + K_CL + 255) / 256, 256, 0, stream>>>(
            partial, cnt_partial, out_counts, out_sums, nsplit);
    } else {
        hipMemsetAsync(out_counts, 0, (size_t)(K_CL + K_CL * D) * sizeof(float), stream);
        scatter_atomic_kernel<<<N_PTS / (16 * 4), 256, 0, stream>>>(
            batch, out_assign, out_counts, out_sums);
    }
}

// Round 7
// 405.828 us; speedup vs baseline: 1.1005x; 1.1005x over previous
//
#include <hip/hip_runtime.h>
#include <float.h>

#define N_PTS 262144
#define K_CL  1024
#define D     64
#define PTS_PER_WAVE   32
#define WAVES_PER_BLK  4
#define PTS_PER_BLK    (PTS_PER_WAVE * WAVES_PER_BLK)   // 128
#define NTILE 8              // 8 tiles of 128 centroids
#define MARGIN_S 0.5f        // score margin (distance margin 1.0; fp16 err bound ~0.07)
#define CAND_CAP 6

typedef _Float16 f16;
typedef _Float16 half8 __attribute__((ext_vector_type(8)));
typedef float    f32x4 __attribute__((ext_vector_type(4)));

// ---- prep: csq (exact fp32), csqhn = -0.5*csq, cent16 = fp16 linear
__global__ __launch_bounds__(256) void prep_kernel(const float* __restrict__ cent,
                                                   float* __restrict__ csq,
                                                   float* __restrict__ csqhn,
                                                   f16* __restrict__ cent16) {
    int k = blockIdx.x * 256 + threadIdx.x;
    if (k >= K_CL) return;
    const float* row = &cent[(size_t)k * D];
    float s = 0.f;
    #pragma unroll
    for (int d = 0; d < D; ++d) s = fmaf(row[d], row[d], s);
    csq[k]   = s;
    csqhn[k] = -0.5f * s;
    #pragma unroll
    for (int ch = 0; ch < 8; ++ch) {
        half8 h;
        #pragma unroll
        for (int e = 0; e < 8; ++e) h[e] = (f16)row[ch * 8 + e];
        *reinterpret_cast<half8*>(&cent16[(size_t)k * D + ch * 8]) = h;
    }
}

// exact fp32 distance, identical arithmetic to the accepted round-1 kernel
__device__ __forceinline__ float exact_dist(const float* __restrict__ xr,
                                            const float* __restrict__ cr,
                                            float xsq, float cs) {
    float dot = 0.f;
    #pragma unroll
    for (int d = 0; d < D; ++d) dot = fmaf(xr[d], cr[d], dot);
    return (xsq - 2.0f * dot) + cs;
}

__device__ __forceinline__ half8 ld_half8(const f16* p) {
    return *reinterpret_cast<const half8*>(p);
}

__device__ __forceinline__ half8 point_frag(const float* __restrict__ batch,
                                            int prow, int chunk) {
    const float* src = &batch[(size_t)prow * D + chunk * 8];
    float4 u0 = *reinterpret_cast<const float4*>(src);
    float4 u1 = *reinterpret_cast<const float4*>(src + 4);
    half8 h;
    h[0] = (f16)u0.x; h[1] = (f16)u0.y; h[2] = (f16)u0.z; h[3] = (f16)u0.w;
    h[4] = (f16)u1.x; h[5] = (f16)u1.y; h[6] = (f16)u1.z; h[7] = (f16)u1.w;
    return h;
}

__device__ __forceinline__ float vmax4(const f32x4& a) {
    return fmaxf(fmaxf(a.x, a.y), fmaxf(a.z, a.w));
}

__device__ __forceinline__ void collect(const f32x4& a, float thr, int cbase, int& cnt,
                                        int& s0, int& s1, int& s2, int& s3, int& s4, int& s5) {
    if (vmax4(a) >= thr) {
        #pragma unroll
        for (int r = 0; r < 4; ++r) {
            if (a[r] >= thr) {
                int c = cbase + r;
                if      (cnt == 0) s0 = c;
                else if (cnt == 1) s1 = c;
                else if (cnt == 2) s2 = c;
                else if (cnt == 3) s3 = c;
                else if (cnt == 4) s4 = c;
                else if (cnt == 5) s5 = c;
                cnt++;
            }
        }
    }
}

__device__ __forceinline__ void resolve(const float* __restrict__ batch,
                                        const float* __restrict__ cent,
                                        const float* __restrict__ csq,
                                        int prow, int hi, int cnt,
                                        int s0, int s1, int s2, int s3, int s4, int s5,
                                        float& bd, int& bi) {
    bd = FLT_MAX; bi = 0x7fffffff;
    if (cnt == 0) return;
    const float* xr = &batch[(size_t)prow * D];
    float xsq = 0.f;
    #pragma unroll
    for (int d = 0; d < D; ++d) xsq = fmaf(xr[d], xr[d], xsq);
    if (cnt <= CAND_CAP) {
        #pragma unroll
        for (int r = 0; r < CAND_CAP; ++r) {
            int c = (r == 0) ? s0 : (r == 1) ? s1 : (r == 2) ? s2
                  : (r == 3) ? s3 : (r == 4) ? s4 : s5;
            if (r < cnt) {
                float dd = exact_dist(xr, &cent[(size_t)c * D], xsq, csq[c]);
                if (dd < bd || (dd == bd && c < bi)) { bd = dd; bi = c; }
            }
        }
    } else {  // overflow (P ~ 0 with final-max threshold): exact scan of lane's slice
        for (int t16 = 0; t16 < 64; ++t16) {
            #pragma unroll
            for (int r = 0; r < 4; ++r) {
                int c = t16 * 16 + hi * 4 + r;
                float dd = exact_dist(xr, &cent[(size_t)c * D], xsq, csq[c]);
                if (dd < bd || (dd == bd && c < bi)) { bd = dd; bi = c; }
            }
        }
    }
}

// launch_bounds (256,4): VGPR cap 128 so no spills; expect ~50-60 VGPR which
// still lets HW run 8 waves/SIMD (occupancy step at 64 VGPR). Round-6's (256,8)
// forced VGPR=32 -> 182 MB scratch spill traffic.
__global__ __launch_bounds__(256, 4) void assign_kernel(
    const float* __restrict__ batch,
    const f16*   __restrict__ cent16,
    const float* __restrict__ csq,
    const float* __restrict__ csqhn,
    const float* __restrict__ cent,
    float* __restrict__ out_assign)
{
    const int tid   = threadIdx.x;
    const int wave  = tid >> 6;
    const int lane  = tid & 63;
    const int lo    = lane & 15;
    const int hi    = lane >> 4;
    const int wbase = (blockIdx.x * WAVES_PER_BLK + wave) * PTS_PER_WAVE;

    const int pr0 = wbase + lo;
    const int pr1 = wbase + 16 + lo;

    // loop-invariant point fragments in registers
    const half8 p0a = point_frag(batch, pr0, hi), p0b = point_frag(batch, pr0, 4 + hi);
    const half8 p1a = point_frag(batch, pr1, hi), p1b = point_frag(batch, pr1, 4 + hi);

    // =================== PASS 1: branch-free final max ===================
    float m0 = -FLT_MAX, m1 = -FLT_MAX;
    for (int t = 0; t < NTILE; ++t) {
        const int base = t * 128;
        #pragma unroll
        for (int m = 0; m < 8; ++m) {
            const int row = base + m * 16 + lo;
            const half8 cf0 = ld_half8(&cent16[(size_t)row * D + hi * 8]);
            const half8 cf1 = ld_half8(&cent16[(size_t)row * D + (4 + hi) * 8]);
            const f32x4 ch  = *reinterpret_cast<const f32x4*>(&csqhn[base + m * 16 + hi * 4]);
            f32x4 a0 = ch, a1 = ch;
            a0 = __builtin_amdgcn_mfma_f32_16x16x32_f16(cf0, p0a, a0, 0, 0, 0);
            a0 = __builtin_amdgcn_mfma_f32_16x16x32_f16(cf1, p0b, a0, 0, 0, 0);
            a1 = __builtin_amdgcn_mfma_f32_16x16x32_f16(cf0, p1a, a1, 0, 0, 0);
            a1 = __builtin_amdgcn_mfma_f32_16x16x32_f16(cf1, p1b, a1, 0, 0, 0);
            m0 = fmaxf(m0, vmax4(a0));
            m1 = fmaxf(m1, vmax4(a1));
        }
    }
    m0 = fmaxf(m0, __shfl_xor(m0, 16)); m0 = fmaxf(m0, __shfl_xor(m0, 32));
    m1 = fmaxf(m1, __shfl_xor(m1, 16)); m1 = fmaxf(m1, __shfl_xor(m1, 32));
    const float t0 = m0 - MARGIN_S, t1 = m1 - MARGIN_S;

    // =================== PASS 2: collect candidates vs final threshold ===================
    int n0 = 0, n1 = 0;
    int a0c0=0,a0c1=0,a0c2=0,a0c3=0,a0c4=0,a0c5=0;
    int a1c0=0,a1c1=0,a1c2=0,a1c3=0,a1c4=0,a1c5=0;

    for (int t = 0; t < NTILE; ++t) {
        const int base = t * 128;
        #pragma unroll
        for (int m = 0; m < 8; ++m) {
            const int row = base + m * 16 + lo;
            const half8 cf0 = ld_half8(&cent16[(size_t)row * D + hi * 8]);
            const half8 cf1 = ld_half8(&cent16[(size_t)row * D + (4 + hi) * 8]);
            const f32x4 ch  = *reinterpret_cast<const f32x4*>(&csqhn[base + m * 16 + hi * 4]);
            f32x4 a0 = ch, a1 = ch;
            a0 = __builtin_amdgcn_mfma_f32_16x16x32_f16(cf0, p0a, a0, 0, 0, 0);
            a0 = __builtin_amdgcn_mfma_f32_16x16x32_f16(cf1, p0b, a0, 0, 0, 0);
            a1 = __builtin_amdgcn_mfma_f32_16x16x32_f16(cf0, p1a, a1, 0, 0, 0);
            a1 = __builtin_amdgcn_mfma_f32_16x16x32_f16(cf1, p1b, a1, 0, 0, 0);
            const int cbase = base + m * 16 + hi * 4;
            collect(a0, t0, cbase, n0, a0c0, a0c1, a0c2, a0c3, a0c4, a0c5);
            collect(a1, t1, cbase, n1, a1c0, a1c1, a1c2, a1c3, a1c4, a1c5);
        }
    }

    // =================== exact fp32 resolve (round-1 arithmetic) ===================
    float bd0, bd1;
    int   bi0, bi1;
    resolve(batch, cent, csq, pr0, hi, n0, a0c0, a0c1, a0c2, a0c3, a0c4, a0c5, bd0, bi0);
    resolve(batch, cent, csq, pr1, hi, n1, a1c0, a1c1, a1c2, a1c3, a1c4, a1c5, bd1, bi1);

    #pragma unroll
    for (int off = 16; off <= 32; off <<= 1) {
        float od; int oi;
        od = __shfl_xor(bd0, off); oi = __shfl_xor(bi0, off);
        if (od < bd0 || (od == bd0 && oi < bi0)) { bd0 = od; bi0 = oi; }
        od = __shfl_xor(bd1, off); oi = __shfl_xor(bi1, off);
        if (od < bd1 || (od == bd1 && oi < bi1)) { bd1 = od; bi1 = oi; }
    }

    if (hi == 0) {
        out_assign[pr0] = (float)bi0;
        out_assign[pr1] = (float)bi1;
    }
}

// ---- scatter with runtime nsplit-way split copies
__global__ __launch_bounds__(256) void scatter_split_kernel(
    const float* __restrict__ batch,
    const float* __restrict__ assignF,
    float* __restrict__ partial,        // [nsplit][K_CL][D]
    float* __restrict__ cnt_partial,    // [nsplit][K_CL]
    int split_mask)
{
    const int gwave = (blockIdx.x * 256 + threadIdx.x) >> 6;   // 16384 waves
    const int lane  = threadIdx.x & 63;
    const int split = blockIdx.x & split_mask;
    float* ps = &partial[(size_t)split * K_CL * D];
    float* cs = &cnt_partial[(size_t)split * K_CL];
    #pragma unroll 4
    for (int it = 0; it < 16; ++it) {
        int p = gwave * 16 + it;
        int a = (int)assignF[p];
        atomicAdd(&ps[(size_t)a * D + lane], batch[(size_t)p * D + lane]);
        if (lane == 0) atomicAdd(&cs[a], 1.0f);
    }
}

__global__ __launch_bounds__(256) void reduce_kernel(
    const float* __restrict__ partial,
    const float* __restrict__ cnt_partial,
    float* __restrict__ out_counts,
    float* __restrict__ out_sums,
    int nsplit)
{
    int idx = blockIdx.x * 256 + threadIdx.x;
    if (idx < K_CL * D) {
        float s = 0.f;
        for (int e = 0; e < nsplit; ++e) s += partial[(size_t)e * K_CL * D + idx];
        out_sums[idx] = s;
    } else if (idx < K_CL * D + K_CL) {
        int c = idx - K_CL * D;
        float s = 0.f;
        for (int e = 0; e < nsplit; ++e) s += cnt_partial[e * K_CL + c];
        out_counts[c] = s;
    }
}

// ---- fallback scatter (single-copy atomics into d_out) if ws is too small
__global__ __launch_bounds__(256) void scatter_atomic_kernel(
    const float* __restrict__ batch,
    const float* __restrict__ assignF,
    float* __restrict__ out_counts,
    float* __restrict__ out_sums)
{
    const int gwave = (blockIdx.x * 256 + threadIdx.x) >> 6;
    const int lane  = threadIdx.x & 63;
    #pragma unroll 4
    for (int it = 0; it < 16; ++it) {
        int p = gwave * 16 + it;
        int a = (int)assignF[p];
        if (lane == 0) atomicAdd(&out_counts[a], 1.0f);
        atomicAdd(&out_sums[(size_t)a * D + lane], batch[(size_t)p * D + lane]);
    }
}

extern "C" void kernel_launch(void* const* d_in, const int* in_sizes, int n_in,
                              void* d_out, int out_size, void* d_ws, size_t ws_size,
                              hipStream_t stream) {
    const float* batch = (const float*)d_in[0];
    const float* cent  = (const float*)d_in[1];
    float* out        = (float*)d_out;
    float* out_assign = out;
    float* out_counts = out + N_PTS;
    float* out_sums   = out + N_PTS + K_CL;

    float* csq    = (float*)d_ws;                                  // 4 KB
    float* csqhn  = csq + K_CL;                                    // 4 KB
    f16*   cent16 = (f16*)((char*)d_ws + 8192);                    // 128 KB
    float* partial = (float*)((char*)d_ws + 8192 + 131072);

    // pick largest nsplit that fits ws (32 -> 16 -> 8 -> fallback)
    int nsplit = 0;
    for (int ns = 32; ns >= 8; ns >>= 1) {
        size_t need = 8192 + 131072 +
                      (size_t)ns * K_CL * D * 4 + (size_t)ns * K_CL * 4;
        if (ws_size >= need) { nsplit = ns; break; }
    }

    prep_kernel<<<K_CL / 256, 256, 0, stream>>>(cent, csq, csqhn, cent16);
    assign_kernel<<<N_PTS / PTS_PER_BLK, 256, 0, stream>>>(
        batch, cent16, csq, csqhn, cent, out_assign);

    if (nsplit > 0) {
        float* cnt_partial = partial + (size_t)nsplit * K_CL * D;
        hipMemsetAsync(partial, 0,
                       (size_t)(nsplit * K_CL * D + nsplit * K_CL) * sizeof(float), stream);
        scatter_split_kernel<<<N_PTS / (16 * 4), 256, 0, stream>>>(
            batch, out_assign, partial, cnt_partial, nsplit - 1);
        reduce_kernel<<<(K_CL * D + K_CL + 255) / 256, 256, 0, stream>>>(
            partial, cnt_partial, out_counts, out_sums, nsplit);
    } else {
        hipMemsetAsync(out_counts, 0, (size_t)(K_CL + K_CL * D) * sizeof(float), stream);
        scatter_atomic_kernel<<<N_PTS / (16 * 4), 256, 0, stream>>>(
            batch, out_assign, out_counts, out_sums);
    }
}

// Round 8
// 188.906 us; speedup vs baseline: 2.3642x; 2.1483x over previous
//
#include <hip/hip_runtime.h>
#include <float.h>

#define N_PTS 262144
#define K_CL  1024
#define D     64
#define PTS_PER_WAVE   64
#define WAVES_PER_BLK  16
#define PTS_PER_BLK    (PTS_PER_WAVE * WAVES_PER_BLK)   // 1024
#define NTILE 8
#define MARGIN_S 0.5f        // score margin (distance margin 1.0; fp16 err bound ~0.1)
#define CAND_CAP 6

typedef _Float16 f16;
typedef _Float16 half8 __attribute__((ext_vector_type(8)));
typedef float    f32x4 __attribute__((ext_vector_type(4)));

// ---- prep: csq (exact fp32), csqhn = -0.5*csq, cent16 = fp16 PRE-SWIZZLED
// phys 16B-chunk pc of row k holds logical chunk pc ^ (k&7) -> LDS copy is linear,
// swizzled ds_read spreads 16 same-hi lanes over all 32 banks (2/bank = free).
__global__ __launch_bounds__(256) void prep_kernel(const float* __restrict__ cent,
                                                   float* __restrict__ csq,
                                                   float* __restrict__ csqhn,
                                                   f16* __restrict__ cent16) {
    int k = blockIdx.x * 256 + threadIdx.x;
    if (k >= K_CL) return;
    const float* row = &cent[(size_t)k * D];
    float s = 0.f;
    #pragma unroll
    for (int d = 0; d < D; ++d) s = fmaf(row[d], row[d], s);
    csq[k]   = s;
    csqhn[k] = -0.5f * s;
    int sw = k & 7;
    #pragma unroll
    for (int ch = 0; ch < 8; ++ch) {
        half8 h;
        #pragma unroll
        for (int e = 0; e < 8; ++e) h[e] = (f16)row[ch * 8 + e];
        *reinterpret_cast<half8*>(&cent16[(size_t)k * D + (size_t)((ch ^ sw) * 8)]) = h;
    }
}

// exact fp32 distance, identical arithmetic to the accepted round-1 kernel
__device__ __forceinline__ float exact_dist(const float* __restrict__ xr,
                                            const float* __restrict__ cr,
                                            float xsq, float cs) {
    float dot = 0.f;
    #pragma unroll
    for (int d = 0; d < D; ++d) dot = fmaf(xr[d], cr[d], dot);
    return (xsq - 2.0f * dot) + cs;
}

__device__ __forceinline__ half8 point_frag(const float* __restrict__ batch,
                                            int prow, int chunk) {
    const float* src = &batch[(size_t)prow * D + chunk * 8];
    float4 u0 = *reinterpret_cast<const float4*>(src);
    float4 u1 = *reinterpret_cast<const float4*>(src + 4);
    half8 h;
    h[0] = (f16)u0.x; h[1] = (f16)u0.y; h[2] = (f16)u0.z; h[3] = (f16)u0.w;
    h[4] = (f16)u1.x; h[5] = (f16)u1.y; h[6] = (f16)u1.z; h[7] = (f16)u1.w;
    return h;
}

__device__ __forceinline__ float vmax4(const f32x4& a) {
    return fmaxf(fmaxf(a.x, a.y), fmaxf(a.z, a.w));
}

__device__ __forceinline__ void collect(const f32x4& a, float thr, int cbase, int& cnt,
                                        int& s0, int& s1, int& s2, int& s3, int& s4, int& s5) {
    if (vmax4(a) >= thr) {
        #pragma unroll
        for (int r = 0; r < 4; ++r) {
            if (a[r] >= thr) {
                int c = cbase + r;
                if      (cnt == 0) s0 = c;
                else if (cnt == 1) s1 = c;
                else if (cnt == 2) s2 = c;
                else if (cnt == 3) s3 = c;
                else if (cnt == 4) s4 = c;
                else if (cnt == 5) s5 = c;
                cnt++;
            }
        }
    }
}

__device__ __forceinline__ void resolve(const float* __restrict__ batch,
                                        const float* __restrict__ cent,
                                        const float* __restrict__ csq,
                                        int prow, int hi, int cnt,
                                        int s0, int s1, int s2, int s3, int s4, int s5,
                                        float& bd, int& bi) {
    bd = FLT_MAX; bi = 0x7fffffff;
    if (cnt == 0) return;
    const float* xr = &batch[(size_t)prow * D];
    float xsq = 0.f;
    #pragma unroll
    for (int d = 0; d < D; ++d) xsq = fmaf(xr[d], xr[d], xsq);
    if (cnt <= CAND_CAP) {
        #pragma unroll
        for (int r = 0; r < CAND_CAP; ++r) {
            int c = (r == 0) ? s0 : (r == 1) ? s1 : (r == 2) ? s2
                  : (r == 3) ? s3 : (r == 4) ? s4 : s5;
            if (r < cnt) {
                float dd = exact_dist(xr, &cent[(size_t)c * D], xsq, csq[c]);
                if (dd < bd || (dd == bd && c < bi)) { bd = dd; bi = c; }
            }
        }
    } else {  // overflow (P ~ 0 with final-max threshold): exact scan of lane's slice
        for (int t16 = 0; t16 < 64; ++t16) {
            #pragma unroll
            for (int r = 0; r < 4; ++r) {
                int c = t16 * 16 + hi * 4 + r;
                float dd = exact_dist(xr, &cent[(size_t)c * D], xsq, csq[c]);
                if (dd < bd || (dd == bd && c < bi)) { bd = dd; bi = c; }
            }
        }
    }
}

// 1024 threads, 16 waves, 1 block/CU. LDS: full centroid set staged ONCE
// (132 KB <= 160 KB/CU), single barrier, then barrier-free MFMA loops from LDS.
// Scatter fused at the tail (atomics overlap other waves' compute).
__global__ __launch_bounds__(1024, 4) void assign_kernel(
    const float* __restrict__ batch,
    const f16*   __restrict__ cent16,
    const float* __restrict__ csq,
    const float* __restrict__ csqhn,
    const float* __restrict__ cent,
    float* __restrict__ out_assign,
    float* __restrict__ ps_base,     // [nsplit][K_CL][D] (or out_sums if direct)
    float* __restrict__ cs_base,     // [nsplit][K_CL]    (or out_counts)
    int split_mask)
{
    __shared__ f16   C16[K_CL * D];              // 128 KB, swizzled phys layout
    __shared__ __align__(16) float CH[K_CL];     // 4 KB (-0.5*csq)

    const int tid   = threadIdx.x;
    const int wave  = tid >> 6;
    const int lane  = tid & 63;
    const int lo    = lane & 15;
    const int hi    = lane >> 4;
    const int wbase = (blockIdx.x * WAVES_PER_BLK + wave) * PTS_PER_WAVE;

    // ---- stage centroids: linear coalesced copy (16B/lane per iter)
    #pragma unroll
    for (int it = 0; it < 8; ++it) {
        int u = tid + 1024 * it;     // half8 index in [0, 8192)
        *reinterpret_cast<half8*>(&C16[u * 8]) =
            *reinterpret_cast<const half8*>(&cent16[(size_t)u * 8]);
    }
    CH[tid] = csqhn[tid];
    __syncthreads();

    const int pr0 = wbase + 0 * 16 + lo;
    const int pr1 = wbase + 1 * 16 + lo;
    const int pr2 = wbase + 2 * 16 + lo;
    const int pr3 = wbase + 3 * 16 + lo;

    const half8 p0a = point_frag(batch, pr0, hi), p0b = point_frag(batch, pr0, 4 + hi);
    const half8 p1a = point_frag(batch, pr1, hi), p1b = point_frag(batch, pr1, 4 + hi);
    const half8 p2a = point_frag(batch, pr2, hi), p2b = point_frag(batch, pr2, 4 + hi);
    const half8 p3a = point_frag(batch, pr3, hi), p3b = point_frag(batch, pr3, 4 + hi);

    // =================== PASS 1: branch-free final max (LDS operands) ===========
    float m0 = -FLT_MAX, m1 = -FLT_MAX, m2 = -FLT_MAX, m3 = -FLT_MAX;
    for (int t = 0; t < NTILE; ++t) {
        const int base = t * 128;
        #pragma unroll
        for (int m = 0; m < 8; ++m) {
            const int row = base + m * 16 + lo;
            const int sw  = row & 7;
            const half8 cf0 = *reinterpret_cast<const half8*>(&C16[row * D + ((hi     ^ sw) * 8)]);
            const half8 cf1 = *reinterpret_cast<const half8*>(&C16[row * D + (((4+hi) ^ sw) * 8)]);
            const f32x4 ch  = *reinterpret_cast<const f32x4*>(&CH[base + m * 16 + hi * 4]);
            f32x4 a0 = ch, a1 = ch, a2 = ch, a3 = ch;
            a0 = __builtin_amdgcn_mfma_f32_16x16x32_f16(cf0, p0a, a0, 0, 0, 0);
            a0 = __builtin_amdgcn_mfma_f32_16x16x32_f16(cf1, p0b, a0, 0, 0, 0);
            a1 = __builtin_amdgcn_mfma_f32_16x16x32_f16(cf0, p1a, a1, 0, 0, 0);
            a1 = __builtin_amdgcn_mfma_f32_16x16x32_f16(cf1, p1b, a1, 0, 0, 0);
            a2 = __builtin_amdgcn_mfma_f32_16x16x32_f16(cf0, p2a, a2, 0, 0, 0);
            a2 = __builtin_amdgcn_mfma_f32_16x16x32_f16(cf1, p2b, a2, 0, 0, 0);
            a3 = __builtin_amdgcn_mfma_f32_16x16x32_f16(cf0, p3a, a3, 0, 0, 0);
            a3 = __builtin_amdgcn_mfma_f32_16x16x32_f16(cf1, p3b, a3, 0, 0, 0);
            m0 = fmaxf(m0, vmax4(a0));
            m1 = fmaxf(m1, vmax4(a1));
            m2 = fmaxf(m2, vmax4(a2));
            m3 = fmaxf(m3, vmax4(a3));
        }
    }
    m0 = fmaxf(m0, __shfl_xor(m0, 16)); m0 = fmaxf(m0, __shfl_xor(m0, 32));
    m1 = fmaxf(m1, __shfl_xor(m1, 16)); m1 = fmaxf(m1, __shfl_xor(m1, 32));
    m2 = fmaxf(m2, __shfl_xor(m2, 16)); m2 = fmaxf(m2, __shfl_xor(m2, 32));
    m3 = fmaxf(m3, __shfl_xor(m3, 16)); m3 = fmaxf(m3, __shfl_xor(m3, 32));
    const float t0 = m0 - MARGIN_S, t1 = m1 - MARGIN_S,
                t2 = m2 - MARGIN_S, t3 = m3 - MARGIN_S;

    // =================== PASS 2: collect candidates vs final threshold ==========
    int n0 = 0, n1 = 0, n2 = 0, n3 = 0;
    int a0c0=0,a0c1=0,a0c2=0,a0c3=0,a0c4=0,a0c5=0;
    int a1c0=0,a1c1=0,a1c2=0,a1c3=0,a1c4=0,a1c5=0;
    int a2c0=0,a2c1=0,a2c2=0,a2c3=0,a2c4=0,a2c5=0;
    int a3c0=0,a3c1=0,a3c2=0,a3c3=0,a3c4=0,a3c5=0;

    for (int t = 0; t < NTILE; ++t) {
        const int base = t * 128;
        #pragma unroll
        for (int m = 0; m < 8; ++m) {
            const int row = base + m * 16 + lo;
            const int sw  = row & 7;
            const half8 cf0 = *reinterpret_cast<const half8*>(&C16[row * D + ((hi     ^ sw) * 8)]);
            const half8 cf1 = *reinterpret_cast<const half8*>(&C16[row * D + (((4+hi) ^ sw) * 8)]);
            const f32x4 ch  = *reinterpret_cast<const f32x4*>(&CH[base + m * 16 + hi * 4]);
            f32x4 a0 = ch, a1 = ch, a2 = ch, a3 = ch;
            a0 = __builtin_amdgcn_mfma_f32_16x16x32_f16(cf0, p0a, a0, 0, 0, 0);
            a0 = __builtin_amdgcn_mfma_f32_16x16x32_f16(cf1, p0b, a0, 0, 0, 0);
            a1 = __builtin_amdgcn_mfma_f32_16x16x32_f16(cf0, p1a, a1, 0, 0, 0);
            a1 = __builtin_amdgcn_mfma_f32_16x16x32_f16(cf1, p1b, a1, 0, 0, 0);
            a2 = __builtin_amdgcn_mfma_f32_16x16x32_f16(cf0, p2a, a2, 0, 0, 0);
            a2 = __builtin_amdgcn_mfma_f32_16x16x32_f16(cf1, p2b, a2, 0, 0, 0);
            a3 = __builtin_amdgcn_mfma_f32_16x16x32_f16(cf0, p3a, a3, 0, 0, 0);
            a3 = __builtin_amdgcn_mfma_f32_16x16x32_f16(cf1, p3b, a3, 0, 0, 0);
            const int cbase = base + m * 16 + hi * 4;
            collect(a0, t0, cbase, n0, a0c0, a0c1, a0c2, a0c3, a0c4, a0c5);
            collect(a1, t1, cbase, n1, a1c0, a1c1, a1c2, a1c3, a1c4, a1c5);
            collect(a2, t2, cbase, n2, a2c0, a2c1, a2c2, a2c3, a2c4, a2c5);
            collect(a3, t3, cbase, n3, a3c0, a3c1, a3c2, a3c3, a3c4, a3c5);
        }
    }

    // =================== exact fp32 resolve (round-1 arithmetic) ================
    float bd0, bd1, bd2, bd3;
    int   bi0, bi1, bi2, bi3;
    resolve(batch, cent, csq, pr0, hi, n0, a0c0, a0c1, a0c2, a0c3, a0c4, a0c5, bd0, bi0);
    resolve(batch, cent, csq, pr1, hi, n1, a1c0, a1c1, a1c2, a1c3, a1c4, a1c5, bd1, bi1);
    resolve(batch, cent, csq, pr2, hi, n2, a2c0, a2c1, a2c2, a2c3, a2c4, a2c5, bd2, bi2);
    resolve(batch, cent, csq, pr3, hi, n3, a3c0, a3c1, a3c2, a3c3, a3c4, a3c5, bd3, bi3);

    #pragma unroll
    for (int off = 16; off <= 32; off <<= 1) {
        float od; int oi;
        od = __shfl_xor(bd0, off); oi = __shfl_xor(bi0, off);
        if (od < bd0 || (od == bd0 && oi < bi0)) { bd0 = od; bi0 = oi; }
        od = __shfl_xor(bd1, off); oi = __shfl_xor(bi1, off);
        if (od < bd1 || (od == bd1 && oi < bi1)) { bd1 = od; bi1 = oi; }
        od = __shfl_xor(bd2, off); oi = __shfl_xor(bi2, off);
        if (od < bd2 || (od == bd2 && oi < bi2)) { bd2 = od; bi2 = oi; }
        od = __shfl_xor(bd3, off); oi = __shfl_xor(bi3, off);
        if (od < bd3 || (od == bd3 && oi < bi3)) { bd3 = od; bi3 = oi; }
    }
    // post-reduce: bi_s uniform across hi for each lo

    if (hi == 0) {
        out_assign[pr0] = (float)bi0;
        out_assign[pr1] = (float)bi1;
        out_assign[pr2] = (float)bi2;
        out_assign[pr3] = (float)bi3;
    }

    // =================== fused scatter (fire-and-forget atomics) ================
    const int split = (blockIdx.x * WAVES_PER_BLK + wave) & split_mask;
    float* ps = ps_base + (size_t)split * K_CL * D;
    float* cs = cs_base + (size_t)split * K_CL;
    #pragma unroll 4
    for (int s = 0; s < 4; ++s) {
        int bis = (s == 0) ? bi0 : (s == 1) ? bi1 : (s == 2) ? bi2 : bi3;
        for (int p = 0; p < 16; ++p) {
            int a = __shfl(bis, p);                      // cluster of point (s,p)
            int pt = wbase + s * 16 + p;
            float v = batch[(size_t)pt * D + lane];      // lane = dim, coalesced
            atomicAdd(&ps[(size_t)a * D + lane], v);
            if (lane == 0) atomicAdd(&cs[a], 1.0f);
        }
    }
}

__global__ __launch_bounds__(256) void reduce_kernel(
    const float* __restrict__ partial,
    const float* __restrict__ cnt_partial,
    float* __restrict__ out_counts,
    float* __restrict__ out_sums,
    int nsplit)
{
    int idx = blockIdx.x * 256 + threadIdx.x;
    if (idx < K_CL * D) {
        float s = 0.f;
        for (int e = 0; e < nsplit; ++e) s += partial[(size_t)e * K_CL * D + idx];
        out_sums[idx] = s;
    } else if (idx < K_CL * D + K_CL) {
        int c = idx - K_CL * D;
        float s = 0.f;
        for (int e = 0; e < nsplit; ++e) s += cnt_partial[e * K_CL + c];
        out_counts[c] = s;
    }
}

extern "C" void kernel_launch(void* const* d_in, const int* in_sizes, int n_in,
                              void* d_out, int out_size, void* d_ws, size_t ws_size,
                              hipStream_t stream) {
    const float* batch = (const float*)d_in[0];
    const float* cent  = (const float*)d_in[1];
    float* out        = (float*)d_out;
    float* out_assign = out;
    float* out_counts = out + N_PTS;
    float* out_sums   = out + N_PTS + K_CL;

    float* csq    = (float*)d_ws;                                  // 4 KB
    float* csqhn  = csq + K_CL;                                    // 4 KB
    f16*   cent16 = (f16*)((char*)d_ws + 8192);                    // 128 KB
    float* partial = (float*)((char*)d_ws + 8192 + 131072);

    // pick largest nsplit that fits ws (32 -> 16 -> 8 -> 4 -> 2 -> direct)
    int nsplit = 0;
    for (int ns = 32; ns >= 2; ns >>= 1) {
        size_t need = 8192 + 131072 +
                      (size_t)ns * K_CL * D * 4 + (size_t)ns * K_CL * 4;
        if (ws_size >= need) { nsplit = ns; break; }
    }

    prep_kernel<<<K_CL / 256, 256, 0, stream>>>(cent, csq, csqhn, cent16);

    if (nsplit > 0) {
        float* cnt_partial = partial + (size_t)nsplit * K_CL * D;
        hipMemsetAsync(partial, 0,
                       (size_t)(nsplit * K_CL * D + nsplit * K_CL) * sizeof(float), stream);
        assign_kernel<<<N_PTS / PTS_PER_BLK, 1024, 0, stream>>>(
            batch, cent16, csq, csqhn, cent, out_assign,
            partial, cnt_partial, nsplit - 1);
        reduce_kernel<<<(K_CL * D + K_CL + 255) / 256, 256, 0, stream>>>(
            partial, cnt_partial, out_counts, out_sums, nsplit);
    } else {
        hipMemsetAsync(out_counts, 0, (size_t)(K_CL + K_CL * D) * sizeof(float), stream);
        assign_kernel<<<N_PTS / PTS_PER_BLK, 1024, 0, stream>>>(
            batch, cent16, csq, csqhn, cent, out_assign,
            out_sums, out_counts, 0);
    }
}